// Round 9
// baseline (1226.059 us; speedup 1.0000x reference)
//
#include <hip/hip_runtime.h>

// Problem constants (from reference setup_inputs)
#define BB   8
#define PP   16384
#define KK   16384
#define NN   16
#define CIN  64
#define REL  3
#define CC   67
#define OUTC 64
#define PITCH_US 104       // ushorts per staged row: 96 data + 8 pad = 208 B

// History: r5 76; r7 61; r9 56; r10 45 (bf16 image, 1.24x); r11/12 spill
// regression (launch_bounds = CUDA min-BLOCKS); r13 2xTLP NULL; r14
// dummy-CL NULL; r15 exec-mask (-2x CLs @16 instr) NULL; r16 +segments
// 1.5x WORSE; r17 dwordx4 (-2x instr @same CLs) NULL; r18 probe round:
// probes sum ~45-52us, EVERY dispatch <40us -> halves are additive, no
// single half reproduces the wall.
// MODEL (fits r10/r13/r15/r16/r17): per-CU vmem cost =
//   max(fixed ~45cyc/instruction, ~6cyc/cacheline).
// r13 sits at the corner (16 instr x max(45,48)): every single-axis attack
// nulls. r15 cut CLs -> floor held; r17 cut instrs -> CL term held.
//
// Round 19: cut BOTH axes. dwordx4 shape (8 instr/quad, r17-verified) +
// exec-masked invalid rows (r15-verified): E[CLs/instr] 16->8 =>
// 8 x max(45,48) ~ 384 cyc/quad, 2x less gather-wall than r13/r17's 768.
// gv zero-init once; masked lanes keep stale finite values, killed by
// m=0 in the FMA (bit-identical output; both ingredients passed before).
// Predicted: main 45.3 -> ~30-34us, FETCH/WRITE unchanged, absmax
// 0.015625. If NULL: model dead -> two-kernel split (gather->ws, GEMM).
// Verified keepers: bpermute broadcast (segment coalescing), xor8 merge +
// butterfly swizzles, bf16 MFMA phase 2, XCD<->batch binding, exact-fit
// 1024-block grid, bf16 feats pre-pass.

typedef short s16x8 __attribute__((ext_vector_type(8)));   // 8 bf16 = 4 VGPRs
typedef float f32x4 __attribute__((ext_vector_type(4)));   // MFMA accum
typedef unsigned int u32x2 __attribute__((ext_vector_type(2)));
typedef unsigned int u32x4 __attribute__((ext_vector_type(4)));

static __device__ __forceinline__ unsigned short bf16_rne(float f) {
    unsigned int u = __float_as_uint(f);
    u += 0x7FFF + ((u >> 16) & 1);          // round-to-nearest-even
    return (unsigned short)(u >> 16);
}

template <int PAT>
static __device__ __forceinline__ float swz_add(float v) {
    return v + __int_as_float(
        __builtin_amdgcn_ds_swizzle(__float_as_int(v), PAT));
}

// ---- pre-pass: feats fp32 -> bf16 (RNE) into workspace ----
__global__ __launch_bounds__(256) void feats_to_bf16_kernel(
    const float* __restrict__ f, unsigned short* __restrict__ o)
{
    const int i = blockIdx.x * 256 + threadIdx.x;   // one float4 per thread
    const float4 v = ((const float4*)f)[i];         // 16B coalesced read
    ushort4 r;
    r.x = bf16_rne(v.x); r.y = bf16_rne(v.y);
    r.z = bf16_rne(v.z); r.w = bf16_rne(v.w);
    ((ushort4*)o)[i] = r;                           // 8B coalesced write
}

__global__ __launch_bounds__(512, 3)   // VGPR cap ~85 (r17: used 40); LDS -> 4 blk/CU
void graphconv_kernel(
    const unsigned short* __restrict__ fbf16,// [B, P, CIN] bf16 (workspace)
    const int*   __restrict__ n_idxs,        // [B, K, N]
    const float* __restrict__ neighbor_rel,  // [B, K, N, REL]
    const int*   __restrict__ neighbor_valid,// [B, K, N]
    const float* __restrict__ Wm,            // [OUTC, CC]
    const float* __restrict__ bvec,          // [OUTC]
    float*       __restrict__ out)           // [B, K, OUTC]
{
    __shared__ __align__(16) unsigned short Wbf[OUTC * PITCH_US];     // 13312 B
    __shared__ __align__(16) unsigned short Stile[8 * 16 * PITCH_US]; // 26624 B

    const int tid = threadIdx.x;

    // ---- one-time: W -> bf16 into LDS, B-layout, cols 67..95 zeroed ----
    {
        unsigned int* w32 = (unsigned int*)Wbf;
        for (int j = tid; j < OUTC * (PITCH_US / 2); j += 512) {
            const int o = j / (PITCH_US / 2);
            const int d = j - o * (PITCH_US / 2);
            const int c0 = 2 * d, c1 = 2 * d + 1;
            const float w0 = (c0 < CC) ? Wm[o * CC + c0] : 0.0f;
            const float w1 = (c1 < CC) ? Wm[o * CC + c1] : 0.0f;
            w32[j] = (unsigned int)bf16_rne(w0) |
                     ((unsigned int)bf16_rne(w1) << 16);
        }
    }
    __syncthreads();

    const int lane = tid & 63;
    const int wave = __builtin_amdgcn_readfirstlane(tid >> 6);  // 0..7
    unsigned short* Sw = &Stile[wave * 16 * PITCH_US];

    // zero own tile once (pad cols 68..95 must stay 0.0 for the MFMA)
    {
        unsigned int* s32 = (unsigned int*)Sw;
        for (int j = lane; j < 16 * (PITCH_US / 2); j += 64) s32[j] = 0u;
    }

    const int b   = blockIdx.x & 7;          // XCD-bound batch (verified)
    const int bib = blockIdx.x >> 3;
    const unsigned short* fb = fbf16 + (size_t)b * ((size_t)PP * CIN);

    const int q     = lane & 15;             // position within 16-lane segment
    const int half  = (lane >> 3) & 1;       // neighbor parity handled by lane
    const int chunk = q & 7;                 // 16B chunk within 128B feat row
    const int permb = (lane & 48) << 2;      // byte index of segment start

    const int kg = (bib * 8 + wave) * 16;    // wave's 16 rows
    const size_t rg = (size_t)b * KK + (size_t)kg;

    // ---- all 4 quads' metadata up-front (off the critical chain) ----
    // cmbA[qd] = id | valid<<14 for (k-row lane>>4, neighbor lane&15)
    int   cmbA[4];
    float rl0[4], rl1[4], rl2[4];
#pragma unroll
    for (int qd = 0; qd < 4; ++qd) {
        const size_t rq = rg + (size_t)(qd * 4);
        const int v = neighbor_valid[rq * NN + lane];   // 256B coalesced
        const int i = n_idxs[rq * NN + lane];           // 256B coalesced
        cmbA[qd] = i | (v << 14);
        const float* relq = neighbor_rel + rq * (NN * REL);
        rl0[qd] = relq[3 * lane + 0];               // 768B coalesced
        rl1[qd] = relq[3 * lane + 1];
        rl2[qd] = relq[3 * lane + 2];
    }

    // gather buffer: zero-init once; masked lanes keep stale FINITE values
    // (previous quad's feats), annihilated by m=0 in the FMA.
    u32x4 gv[8];
#pragma unroll
    for (int n = 0; n < 8; ++n) gv[n] = (u32x4){0u, 0u, 0u, 0u};

    // ---- phase 1: 4 quads of 4 rows -> bf16 staging tile ----
    for (int qd = 0; qd < 4; ++qd) {
        const int   cmb = cmbA[qd];
        const float msf = (float)(cmb >> 14);
        float mr0 = msf * rl0[qd];
        float mr1 = msf * rl1[qd];
        float mr2 = msf * rl2[qd];

        // 8 bpermutes: lane gets (id|valid) of (k-row sub, neighbor 2n+half)
        int cm[8];
#pragma unroll
        for (int n = 0; n < 8; ++n)
            cm[n] = __builtin_amdgcn_ds_bpermute(
                permb + ((2 * n + half) << 2), cmb);

        // 8 PREDICATED dwordx4 gathers (16B/lane): segment = 2 rows x
        // 8 lanes x 16B. Invalid rows exec-masked off -> E[CLs/instr]
        // 16 -> 8. BOTH cost axes cut vs r13 (instr 16->8, CLs at floor).
#pragma unroll
        for (int n = 0; n < 8; ++n) {
            if (cm[n] & 0x4000) {
                const int off = ((cm[n] & 0x3FFF) << 6) + (chunk << 3);
                gv[n] = *(const u32x4*)(fb + off);
            }
        }
        __builtin_amdgcn_sched_barrier(0);        // loads stay hoisted

        // unpack: lane accumulates 8 channels over its parity-half (8 nbrs)
        float s0 = 0.f, s1 = 0.f, s2 = 0.f, s3 = 0.f;
        float s4 = 0.f, s5 = 0.f, s6 = 0.f, s7 = 0.f;
        float cnt = 0.f;
#pragma unroll
        for (int n = 0; n < 8; ++n) {
            const float m = (float)(cm[n] >> 14);
            cnt += m;
            const unsigned u0 = gv[n].x, u1 = gv[n].y;
            const unsigned u2 = gv[n].z, u3 = gv[n].w;
            s0 = fmaf(m, __uint_as_float(u0 << 16), s0);
            s1 = fmaf(m, __uint_as_float(u0 & 0xFFFF0000u), s1);
            s2 = fmaf(m, __uint_as_float(u1 << 16), s2);
            s3 = fmaf(m, __uint_as_float(u1 & 0xFFFF0000u), s3);
            s4 = fmaf(m, __uint_as_float(u2 << 16), s4);
            s5 = fmaf(m, __uint_as_float(u2 & 0xFFFF0000u), s5);
            s6 = fmaf(m, __uint_as_float(u3 << 16), s6);
            s7 = fmaf(m, __uint_as_float(u3 & 0xFFFF0000u), s7);
        }

        // merge parity halves: lane q <-> q^8 (xor8 swizzle), 9 values
        cnt = swz_add<0x201F>(cnt);
        s0 = swz_add<0x201F>(s0); s1 = swz_add<0x201F>(s1);
        s2 = swz_add<0x201F>(s2); s3 = swz_add<0x201F>(s3);
        s4 = swz_add<0x201F>(s4); s5 = swz_add<0x201F>(s5);
        s6 = swz_add<0x201F>(s6); s7 = swz_add<0x201F>(s7);

        // segment(16-lane) butterfly for the 3 masked rel sums
        mr0 = swz_add<0x041F>(mr0); mr1 = swz_add<0x041F>(mr1); mr2 = swz_add<0x041F>(mr2);
        mr0 = swz_add<0x081F>(mr0); mr1 = swz_add<0x081F>(mr1); mr2 = swz_add<0x081F>(mr2);
        mr0 = swz_add<0x101F>(mr0); mr1 = swz_add<0x101F>(mr1); mr2 = swz_add<0x101F>(mr2);
        mr0 = swz_add<0x201F>(mr0); mr1 = swz_add<0x201F>(mr1); mr2 = swz_add<0x201F>(mr2);

        const float inv = (cnt > 0.f) ? (1.0f / cnt) : 0.0f;

        const int rowl = qd * 4 + (lane >> 4);   // row within 16-row tile
        if (q < 8) {                             // 8 lanes x 16B = 128B row
            u32x4 pv;
            pv.x = (unsigned)bf16_rne(s0 * inv) |
                   ((unsigned)bf16_rne(s1 * inv) << 16);
            pv.y = (unsigned)bf16_rne(s2 * inv) |
                   ((unsigned)bf16_rne(s3 * inv) << 16);
            pv.z = (unsigned)bf16_rne(s4 * inv) |
                   ((unsigned)bf16_rne(s5 * inv) << 16);
            pv.w = (unsigned)bf16_rne(s6 * inv) |
                   ((unsigned)bf16_rne(s7 * inv) << 16);
            *(u32x4*)(&Sw[rowl * PITCH_US + chunk * 8]) = pv;  // ds_write_b128
        }
        if (q == 0) {                      // rel -> ch 64..66 (+0 pad 67)
            u32x2 ev;
            ev.x = (unsigned)bf16_rne(mr0 * inv) |
                   ((unsigned)bf16_rne(mr1 * inv) << 16);
            ev.y = (unsigned)bf16_rne(mr2 * inv);
            *(u32x2*)(&Sw[rowl * PITCH_US + 64]) = ev;
        }
    }

    // ---- phase 2: 16x64 = S(16x96) x W^T(96x64) on the MFMA pipe ----
    f32x4 C0 = {0.f,0.f,0.f,0.f}, C1 = {0.f,0.f,0.f,0.f};
    f32x4 C2 = {0.f,0.f,0.f,0.f}, C3 = {0.f,0.f,0.f,0.f};
#pragma unroll
    for (int p = 0; p < 3; ++p) {
        const int ko = p * 32 + (lane >> 4) * 8;
        const s16x8 A  = *(const s16x8*)&Sw[(lane & 15) * PITCH_US + ko];
        const s16x8 B0 = *(const s16x8*)&Wbf[( 0 + (lane & 15)) * PITCH_US + ko];
        const s16x8 B1 = *(const s16x8*)&Wbf[(16 + (lane & 15)) * PITCH_US + ko];
        const s16x8 B2 = *(const s16x8*)&Wbf[(32 + (lane & 15)) * PITCH_US + ko];
        const s16x8 B3 = *(const s16x8*)&Wbf[(48 + (lane & 15)) * PITCH_US + ko];
        C0 = __builtin_amdgcn_mfma_f32_16x16x32_bf16(A, B0, C0, 0, 0, 0);
        C1 = __builtin_amdgcn_mfma_f32_16x16x32_bf16(A, B1, C1, 0, 0, 0);
        C2 = __builtin_amdgcn_mfma_f32_16x16x32_bf16(A, B2, C2, 0, 0, 0);
        C3 = __builtin_amdgcn_mfma_f32_16x16x32_bf16(A, B3, C3, 0, 0, 0);
    }

    // ---- epilogue: C/D layout col=lane&15, row=(lane>>4)*4+r ----
    const float bias0 = bvec[ 0 + (lane & 15)];
    const float bias1 = bvec[16 + (lane & 15)];
    const float bias2 = bvec[32 + (lane & 15)];
    const float bias3 = bvec[48 + (lane & 15)];
    const int m0 = (lane >> 4) * 4;
    const int oc = lane & 15;
#pragma unroll
    for (int r = 0; r < 4; ++r) {
        const size_t orow = ((size_t)b * KK + (size_t)(kg + m0 + r)) * OUTC;
        out[orow + 0  + oc] = fmaxf(C0[r] + bias0, 0.0f);
        out[orow + 16 + oc] = fmaxf(C1[r] + bias1, 0.0f);
        out[orow + 32 + oc] = fmaxf(C2[r] + bias2, 0.0f);
        out[orow + 48 + oc] = fmaxf(C3[r] + bias3, 0.0f);
    }
}

extern "C" void kernel_launch(void* const* d_in, const int* in_sizes, int n_in,
                              void* d_out, int out_size, void* d_ws, size_t ws_size,
                              hipStream_t stream) {
    // setup_inputs order: keys(0), points(1), feats(2), n_idxs(3),
    // neighbor_rel(4), neighbor_valid(5), W(6), b(7). keys/points unused.
    const float* feats = (const float*)d_in[2];
    const int*   nidx  = (const int*)  d_in[3];
    const float* nrel  = (const float*)d_in[4];
    const int*   nval  = (const int*)  d_in[5];
    const float* Wm    = (const float*)d_in[6];
    const float* bv    = (const float*)d_in[7];
    float* out = (float*)d_out;

    // workspace: bf16 feats image, 8*16384*64*2 = 16.78 MB (re-written every
    // call; harness re-poisons ws, so no state carried between calls)
    unsigned short* fbf16 = (unsigned short*)d_ws;

    // pre-pass: 8.39M floats / 4 per thread = 2.097M threads = 8192 blocks
    feats_to_bf16_kernel<<<dim3(8192), dim3(256), 0, stream>>>(feats, fbf16);

    // main: 1024 blocks x 512 threads = 128 blocks/batch (b = blockIdx&7 ->
    // XCD binding); LDS 39936B/block -> up to 4 blk/CU; 8 waves x 16 rows
    // x 1024 blocks = 131072 rows.
    graphconv_kernel<<<dim3(1024), dim3(512), 0, stream>>>(
        fbf16, nidx, nrel, nval, Wm, bv, out);
}

// Round 10
// 155.565 us; speedup vs baseline: 7.8813x; 7.8813x over previous
//
#include <hip/hip_runtime.h>

// Problem constants (from reference setup_inputs)
#define BB   8
#define PP   16384
#define KK   16384
#define NN   16
#define CIN  64
#define REL  3
#define CC   67
#define OUTC 64
#define PITCH_US 104       // ushorts per staged row: 96 data + 8 pad = 208 B

// History: r10 45us (bf16 image); r11/12 spill regression; r13 2xTLP NULL;
// r14 dummy-CL NULL; r15 exec-mask NULL; r16 +segments 1.5x WORSE; r17
// -2x instr NULL; r18 probes additive, all <40us; r19 dwordx4+predication
// SCRATCH DISASTER (VGPR 84, WRITE 4.3GB -> predicated wide arrays spill).
// UNIFIED MODEL (fits all rounds): vmem cost ~12 cyc per 16-lane
// coalesce-run SEGMENT, independent of exec mask / destination / bytes
// (weak byte term). r13=r17=64 seg/quad -> equal times. 8192 seg/CU x 12
// ~ 98k cyc ~ 41us = the wall. Only NOT-ISSUING instructions removes
// segments; r15's execz skips existed but fired at P~6% (random validity).
//
// Round 20: per-row COMPACTION so execz skips fire. Pre-pass stably
// compacts each k-row's 16 (id|valid<<14) slots (ballot+popcount prefix +
// ds_permute push; 25MB traffic ~5us). Main kernel = r15 VERBATIM (44us,
// VGPR 56, passed) reading compacted words: slot n all-invalid iff
// n >= max(cnt of the instr's 4 rows) -> E[instr] 16 -> ~11.3/quad,
// segments 64 -> ~45 (-30%). Sum reorder = fp32-only, << tolerance.
// ws = 256MiB (fill trace); we use 16.8MB (fbf16) + 8.4MB (cmb).
// Predicted: main 44 -> 33-37us, total ~140-145, absmax ~0.015625.
// PRE-COMMIT: if main >= 42us, segment model falsified -> revert to r13
// next round and declare the floor.

typedef short s16x8 __attribute__((ext_vector_type(8)));   // 8 bf16 = 4 VGPRs
typedef float f32x4 __attribute__((ext_vector_type(4)));   // MFMA accum
typedef unsigned int u32x2 __attribute__((ext_vector_type(2)));

static __device__ __forceinline__ unsigned short bf16_rne(float f) {
    unsigned int u = __float_as_uint(f);
    u += 0x7FFF + ((u >> 16) & 1);          // round-to-nearest-even
    return (unsigned short)(u >> 16);
}

template <int PAT>
static __device__ __forceinline__ float swz_add(float v) {
    return v + __int_as_float(
        __builtin_amdgcn_ds_swizzle(__float_as_int(v), PAT));
}

// ---- pre-pass 1: feats fp32 -> bf16 (RNE) into workspace ----
__global__ __launch_bounds__(256) void feats_to_bf16_kernel(
    const float* __restrict__ f, unsigned short* __restrict__ o)
{
    const int i = blockIdx.x * 256 + threadIdx.x;   // one float4 per thread
    const float4 v = ((const float4*)f)[i];         // 16B coalesced read
    ushort4 r;
    r.x = bf16_rne(v.x); r.y = bf16_rne(v.y);
    r.z = bf16_rne(v.z); r.w = bf16_rne(v.w);
    ((ushort4*)o)[i] = r;                           // 8B coalesced write
}

// ---- pre-pass 2: per-row stable compaction of (id|valid) slots ----
// Each 16-lane segment = one k-row; valid slots move to the front
// (stable), invalid to the back, via ballot+popcount prefix + ds_permute.
__global__ __launch_bounds__(256) void compact_kernel(
    const int* __restrict__ n_idxs,        // [B*K*N]
    const int* __restrict__ neighbor_valid,// [B*K*N]
    int*       __restrict__ cmbo)          // [B*K*N] compacted id|valid<<14
{
    const int tid = blockIdx.x * 256 + threadIdx.x;   // one slot per thread
    const int id  = n_idxs[tid];                      // 256B coalesced
    const int vl  = neighbor_valid[tid];              // 256B coalesced

    const unsigned long long bal = __ballot(vl != 0);
    const int lane = threadIdx.x & 63;
    const int seg  = lane >> 4;
    const unsigned msk = (unsigned)((bal >> (seg * 16)) & 0xFFFFull);
    const int q = lane & 15;
    const unsigned below = (1u << q) - 1u;
    const int cntseg = __popc(msk);
    const int pos = vl ? __popc(msk & below)
                       : cntseg + __popc((~msk) & below);
    const int permb = (lane & 48) << 2;               // segment base (bytes)
    const int cmb = id | (vl << 14);
    // push own cmb to compacted position; receive the one targeting us
    cmbo[tid] = __builtin_amdgcn_ds_permute(permb + (pos << 2), cmb);
}

__global__ __launch_bounds__(512, 4)   // 4 blocks/CU -> 8 w/SIMD -> VGPR<=64
void graphconv_kernel(
    const unsigned short* __restrict__ fbf16,// [B, P, CIN] bf16 (workspace)
    const int*   __restrict__ cmbc,          // [B, K, N] compacted id|valid
    const float* __restrict__ neighbor_rel,  // [B, K, N, REL]
    const int*   __restrict__ neighbor_valid,// [B, K, N]
    const float* __restrict__ Wm,            // [OUTC, CC]
    const float* __restrict__ bvec,          // [OUTC]
    float*       __restrict__ out)           // [B, K, OUTC]
{
    __shared__ __align__(16) unsigned short Wbf[OUTC * PITCH_US];     // 13312 B
    __shared__ __align__(16) unsigned short Stile[8 * 16 * PITCH_US]; // 26624 B

    const int tid = threadIdx.x;

    // ---- one-time: W -> bf16 into LDS, B-layout, cols 67..95 zeroed ----
    {
        unsigned int* w32 = (unsigned int*)Wbf;
        for (int j = tid; j < OUTC * (PITCH_US / 2); j += 512) {
            const int o = j / (PITCH_US / 2);
            const int d = j - o * (PITCH_US / 2);
            const int c0 = 2 * d, c1 = 2 * d + 1;
            const float w0 = (c0 < CC) ? Wm[o * CC + c0] : 0.0f;
            const float w1 = (c1 < CC) ? Wm[o * CC + c1] : 0.0f;
            w32[j] = (unsigned int)bf16_rne(w0) |
                     ((unsigned int)bf16_rne(w1) << 16);
        }
    }
    __syncthreads();

    const int lane = tid & 63;
    const int wave = __builtin_amdgcn_readfirstlane(tid >> 6);  // 0..7
    unsigned short* Sw = &Stile[wave * 16 * PITCH_US];

    // zero own tile once (pad cols 68..95 must stay 0.0 for the MFMA)
    {
        unsigned int* s32 = (unsigned int*)Sw;
        for (int j = lane; j < 16 * (PITCH_US / 2); j += 64) s32[j] = 0u;
    }

    const int b   = blockIdx.x & 7;          // XCD-bound batch (verified)
    const int bib = blockIdx.x >> 3;
    const unsigned short* fb = fbf16 + (size_t)b * ((size_t)PP * CIN);

    const int q     = lane & 15;             // channel quarter (cols 4q..4q+3)
    const int permb = (lane & 48) << 2;      // byte index of segment start

    const int kg = (bib * 8 + wave) * 16;    // wave's 16 rows
    const size_t rg = (size_t)b * KK + (size_t)kg;

    // ---- all 4 quads' metadata up-front (off the critical chain) ----
    int   vld[4], cwd[4];
    float rl0[4], rl1[4], rl2[4];
#pragma unroll
    for (int qd = 0; qd < 4; ++qd) {
        const size_t rq = rg + (size_t)(qd * 4);
        vld[qd] = neighbor_valid[rq * NN + lane];   // 256B coalesced
        cwd[qd] = cmbc[rq * NN + lane];             // 256B coalesced (compacted)
        const float* relq = neighbor_rel + rq * (NN * REL);
        rl0[qd] = relq[3 * lane + 0];               // 768B coalesced
        rl1[qd] = relq[3 * lane + 1];
        rl2[qd] = relq[3 * lane + 2];
    }

    // gather buffer: zero-init ONCE; stale values are finite (prior feats)
    // and multiplied by m=0 -> result unchanged (r15-verified pattern).
    u32x2 gv[NN];
#pragma unroll
    for (int n = 0; n < NN; ++n) gv[n] = (u32x2){0u, 0u};

    // ---- phase 1: 4 quads of 4 rows -> bf16 staging tile ----
    for (int qd = 0; qd < 4; ++qd) {
        const int   cmb = cwd[qd];                 // compacted id|valid<<14
        const float msf = (float)vld[qd];          // ORIGINAL slot validity
        float mr0 = msf * rl0[qd];
        float mr1 = msf * rl1[qd];
        float mr2 = msf * rl2[qd];
        float cnt = msf;

        // 16 bpermutes: broadcast compacted slot n to the 16-lane segment
        int cm[NN];
#pragma unroll
        for (int n = 0; n < NN; ++n)
            cm[n] = __builtin_amdgcn_ds_bpermute(permb + 4 * n, cmb);

        // 16 PREDICATED dwordx2 gathers. After compaction, high-n slots
        // are invalid for ALL rows -> s_cbranch_execz skips the whole
        // instruction: E[executed] ~ 11.3/16, segments 64 -> ~45/quad.
#pragma unroll
        for (int n = 0; n < NN; ++n) {
            if (cm[n] & 0x4000) {
                const int off = ((cm[n] & 0x3FFF) << 6) + 4 * q; // ushorts
                gv[n] = *(const u32x2*)(fb + off);
            }
        }
        __builtin_amdgcn_sched_barrier(0);        // loads stay hoisted

        float s0 = 0.f, s1 = 0.f, s2 = 0.f, s3 = 0.f;
#pragma unroll
        for (int n = 0; n < NN; ++n) {            // unpack bf16 + fma
            const float m = (float)(cm[n] >> 14);
            const unsigned ux = gv[n].x, uy = gv[n].y;
            s0 = fmaf(m, __uint_as_float(ux << 16), s0);
            s1 = fmaf(m, __uint_as_float(ux & 0xFFFF0000u), s1);
            s2 = fmaf(m, __uint_as_float(uy << 16), s2);
            s3 = fmaf(m, __uint_as_float(uy & 0xFFFF0000u), s3);
        }

        // segment(16-lane) butterfly: count + 3 masked rel sums
        cnt = swz_add<0x041F>(cnt); mr0 = swz_add<0x041F>(mr0);
        mr1 = swz_add<0x041F>(mr1); mr2 = swz_add<0x041F>(mr2);
        cnt = swz_add<0x081F>(cnt); mr0 = swz_add<0x081F>(mr0);
        mr1 = swz_add<0x081F>(mr1); mr2 = swz_add<0x081F>(mr2);
        cnt = swz_add<0x101F>(cnt); mr0 = swz_add<0x101F>(mr0);
        mr1 = swz_add<0x101F>(mr1); mr2 = swz_add<0x101F>(mr2);
        cnt = swz_add<0x201F>(cnt); mr0 = swz_add<0x201F>(mr0);
        mr1 = swz_add<0x201F>(mr1); mr2 = swz_add<0x201F>(mr2);

        const float inv = (cnt > 0.f) ? (1.0f / cnt) : 0.0f;

        const int rowl = qd * 4 + (lane >> 4);   // row within 16-row tile
        u32x2 pv;
        pv.x = (unsigned)bf16_rne(s0 * inv) |
               ((unsigned)bf16_rne(s1 * inv) << 16);
        pv.y = (unsigned)bf16_rne(s2 * inv) |
               ((unsigned)bf16_rne(s3 * inv) << 16);
        *(u32x2*)(&Sw[rowl * PITCH_US + 4 * q]) = pv;     // ds_write_b64
        if (q == 0) {                      // rel -> ch 64..66 (+0 pad 67)
            u32x2 ev;
            ev.x = (unsigned)bf16_rne(mr0 * inv) |
                   ((unsigned)bf16_rne(mr1 * inv) << 16);
            ev.y = (unsigned)bf16_rne(mr2 * inv);
            *(u32x2*)(&Sw[rowl * PITCH_US + 64]) = ev;
        }
    }

    // ---- phase 2: 16x64 = S(16x96) x W^T(96x64) on the MFMA pipe ----
    f32x4 C0 = {0.f,0.f,0.f,0.f}, C1 = {0.f,0.f,0.f,0.f};
    f32x4 C2 = {0.f,0.f,0.f,0.f}, C3 = {0.f,0.f,0.f,0.f};
#pragma unroll
    for (int p = 0; p < 3; ++p) {
        const int ko = p * 32 + (lane >> 4) * 8;
        const s16x8 A  = *(const s16x8*)&Sw[(lane & 15) * PITCH_US + ko];
        const s16x8 B0 = *(const s16x8*)&Wbf[( 0 + (lane & 15)) * PITCH_US + ko];
        const s16x8 B1 = *(const s16x8*)&Wbf[(16 + (lane & 15)) * PITCH_US + ko];
        const s16x8 B2 = *(const s16x8*)&Wbf[(32 + (lane & 15)) * PITCH_US + ko];
        const s16x8 B3 = *(const s16x8*)&Wbf[(48 + (lane & 15)) * PITCH_US + ko];
        C0 = __builtin_amdgcn_mfma_f32_16x16x32_bf16(A, B0, C0, 0, 0, 0);
        C1 = __builtin_amdgcn_mfma_f32_16x16x32_bf16(A, B1, C1, 0, 0, 0);
        C2 = __builtin_amdgcn_mfma_f32_16x16x32_bf16(A, B2, C2, 0, 0, 0);
        C3 = __builtin_amdgcn_mfma_f32_16x16x32_bf16(A, B3, C3, 0, 0, 0);
    }

    // ---- epilogue: C/D layout col=lane&15, row=(lane>>4)*4+r ----
    const float bias0 = bvec[ 0 + (lane & 15)];
    const float bias1 = bvec[16 + (lane & 15)];
    const float bias2 = bvec[32 + (lane & 15)];
    const float bias3 = bvec[48 + (lane & 15)];
    const int m0 = (lane >> 4) * 4;
    const int oc = lane & 15;
#pragma unroll
    for (int r = 0; r < 4; ++r) {
        const size_t orow = ((size_t)b * KK + (size_t)(kg + m0 + r)) * OUTC;
        out[orow + 0  + oc] = fmaxf(C0[r] + bias0, 0.0f);
        out[orow + 16 + oc] = fmaxf(C1[r] + bias1, 0.0f);
        out[orow + 32 + oc] = fmaxf(C2[r] + bias2, 0.0f);
        out[orow + 48 + oc] = fmaxf(C3[r] + bias3, 0.0f);
    }
}

extern "C" void kernel_launch(void* const* d_in, const int* in_sizes, int n_in,
                              void* d_out, int out_size, void* d_ws, size_t ws_size,
                              hipStream_t stream) {
    // setup_inputs order: keys(0), points(1), feats(2), n_idxs(3),
    // neighbor_rel(4), neighbor_valid(5), W(6), b(7). keys/points unused.
    const float* feats = (const float*)d_in[2];
    const int*   nidx  = (const int*)  d_in[3];
    const float* nrel  = (const float*)d_in[4];
    const int*   nval  = (const int*)  d_in[5];
    const float* Wm    = (const float*)d_in[6];
    const float* bv    = (const float*)d_in[7];
    float* out = (float*)d_out;

    // workspace (256 MiB per fill trace): bf16 feats image 16.78 MB,
    // then compacted cmb array 8.39 MB. Both re-written every call.
    unsigned short* fbf16 = (unsigned short*)d_ws;
    int* cmb = (int*)((char*)d_ws + (size_t)BB * PP * CIN * sizeof(unsigned short));

    // pre-pass 1: 8.39M floats / 4 per thread = 8192 blocks
    feats_to_bf16_kernel<<<dim3(8192), dim3(256), 0, stream>>>(feats, fbf16);

    // pre-pass 2: 2.097M slots / 256 per block = 8192 blocks
    compact_kernel<<<dim3(8192), dim3(256), 0, stream>>>(nidx, nval, cmb);

    // main: 1024 blocks x 512 threads, XCD<->batch binding, exact-fit
    // 4 blocks/CU (LDS 39936B), 8 waves x 16 rows x 1024 blocks = 131072.
    graphconv_kernel<<<dim3(1024), dim3(512), 0, stream>>>(
        fbf16, cmb, nrel, nval, Wm, bv, out);
}

// Round 11
// 149.139 us; speedup vs baseline: 8.2209x; 1.0431x over previous
//
#include <hip/hip_runtime.h>

// Problem constants (from reference setup_inputs)
#define BB   8
#define PP   16384
#define KK   16384
#define NN   16
#define CIN  64
#define REL  3
#define CC   67
#define OUTC 64
#define PITCH_US 104       // ushorts per staged row: 96 data + 8 pad = 208 B

// History: r10 45us (bf16 image); r13 2xTLP NULL; r14 dummy-CL NULL; r15
// exec-mask NULL (masked segments still cost); r16 +segments 1.5x WORSE;
// r17 -2x instr NULL; r19 predicated-dwordx4 scratch disaster; r20
// per-row COMPACTION: main 44.5 -> 40.5 (FIRST main win: whole-instruction
// execz skips pay; E[instr] 16 -> ~11/quad) BUT total dur_us unchanged --
// the 5us compact_kernel pre-pass ate the 4us main win. dur_us = fixed
// ~100us harness re-poison + SUM OF OUR DISPATCHES (r0: 8+45=53; r20:
// 8+5+41=54).
//
// Round 21: keep the win, delete its cost. Compaction folded INTO the
// main kernel's metadata phase: ballot + popcount-prefix + 1 ds_permute
// per quad (verified r20 logic verbatim; bijective within each 16-lane
// segment -> every lane receives valid data). cnt = popc(mask) for free
// -> 4 fewer ds_swizzle/quad. compact_kernel dispatch DELETED.
// Predicted: main 40-41 (unchanged +-1), VGPR ~56-60 no spill, absmax
// 0.015625, total dur_us 155.6 -> ~149-151. PRE-COMMIT: if total doesn't
// drop >=3us, dispatch-sum model of dur_us is wrong -> declare floor.
// Verified keepers: bpermute broadcast (segment coalescing), predicated
// dwordx2 gathers + gv zero-init-once, butterfly swizzles (rel), bf16
// MFMA phase 2, XCD<->batch binding, exact-fit 1024-block grid, bf16
// feats pre-pass, __launch_bounds__(512,4).

typedef short s16x8 __attribute__((ext_vector_type(8)));   // 8 bf16 = 4 VGPRs
typedef float f32x4 __attribute__((ext_vector_type(4)));   // MFMA accum
typedef unsigned int u32x2 __attribute__((ext_vector_type(2)));

static __device__ __forceinline__ unsigned short bf16_rne(float f) {
    unsigned int u = __float_as_uint(f);
    u += 0x7FFF + ((u >> 16) & 1);          // round-to-nearest-even
    return (unsigned short)(u >> 16);
}

template <int PAT>
static __device__ __forceinline__ float swz_add(float v) {
    return v + __int_as_float(
        __builtin_amdgcn_ds_swizzle(__float_as_int(v), PAT));
}

// ---- pre-pass: feats fp32 -> bf16 (RNE) into workspace ----
__global__ __launch_bounds__(256) void feats_to_bf16_kernel(
    const float* __restrict__ f, unsigned short* __restrict__ o)
{
    const int i = blockIdx.x * 256 + threadIdx.x;   // one float4 per thread
    const float4 v = ((const float4*)f)[i];         // 16B coalesced read
    ushort4 r;
    r.x = bf16_rne(v.x); r.y = bf16_rne(v.y);
    r.z = bf16_rne(v.z); r.w = bf16_rne(v.w);
    ((ushort4*)o)[i] = r;                           // 8B coalesced write
}

__global__ __launch_bounds__(512, 4)   // 4 blocks/CU -> 8 w/SIMD -> VGPR<=64
void graphconv_kernel(
    const unsigned short* __restrict__ fbf16,// [B, P, CIN] bf16 (workspace)
    const int*   __restrict__ n_idxs,        // [B, K, N]
    const float* __restrict__ neighbor_rel,  // [B, K, N, REL]
    const int*   __restrict__ neighbor_valid,// [B, K, N]
    const float* __restrict__ Wm,            // [OUTC, CC]
    const float* __restrict__ bvec,          // [OUTC]
    float*       __restrict__ out)           // [B, K, OUTC]
{
    __shared__ __align__(16) unsigned short Wbf[OUTC * PITCH_US];     // 13312 B
    __shared__ __align__(16) unsigned short Stile[8 * 16 * PITCH_US]; // 26624 B

    const int tid = threadIdx.x;

    // ---- one-time: W -> bf16 into LDS, B-layout, cols 67..95 zeroed ----
    {
        unsigned int* w32 = (unsigned int*)Wbf;
        for (int j = tid; j < OUTC * (PITCH_US / 2); j += 512) {
            const int o = j / (PITCH_US / 2);
            const int d = j - o * (PITCH_US / 2);
            const int c0 = 2 * d, c1 = 2 * d + 1;
            const float w0 = (c0 < CC) ? Wm[o * CC + c0] : 0.0f;
            const float w1 = (c1 < CC) ? Wm[o * CC + c1] : 0.0f;
            w32[j] = (unsigned int)bf16_rne(w0) |
                     ((unsigned int)bf16_rne(w1) << 16);
        }
    }
    __syncthreads();

    const int lane = tid & 63;
    const int wave = __builtin_amdgcn_readfirstlane(tid >> 6);  // 0..7
    unsigned short* Sw = &Stile[wave * 16 * PITCH_US];

    // zero own tile once (pad cols 68..95 must stay 0.0 for the MFMA)
    {
        unsigned int* s32 = (unsigned int*)Sw;
        for (int j = lane; j < 16 * (PITCH_US / 2); j += 64) s32[j] = 0u;
    }

    const int b   = blockIdx.x & 7;          // XCD-bound batch (verified)
    const int bib = blockIdx.x >> 3;
    const unsigned short* fb = fbf16 + (size_t)b * ((size_t)PP * CIN);

    const int q     = lane & 15;             // channel quarter (cols 4q..4q+3)
    const int seg   = lane >> 4;             // row-within-quad (0..3)
    const int permb = (lane & 48) << 2;      // byte index of segment start

    const int kg = (bib * 8 + wave) * 16;    // wave's 16 rows
    const size_t rg = (size_t)b * KK + (size_t)kg;

    // ---- metadata + INLINE COMPACTION (r20 logic, folded in) ----
    // cwd[qd] = per-segment stably-compacted (id | valid<<14); scf[qd] =
    // (float)valid-count of own row; vldf[qd] = own ORIGINAL slot validity
    // (rel values stay slot-ordered).
    int   cwd[4];
    float scf[4], vldf[4];
    float rl0[4], rl1[4], rl2[4];
#pragma unroll
    for (int qd = 0; qd < 4; ++qd) {
        const size_t rq = rg + (size_t)(qd * 4);
        const int vl = neighbor_valid[rq * NN + lane];  // 256B coalesced
        const int id = n_idxs[rq * NN + lane];          // 256B coalesced
        const float* relq = neighbor_rel + rq * (NN * REL);
        rl0[qd] = relq[3 * lane + 0];                   // 768B coalesced
        rl1[qd] = relq[3 * lane + 1];
        rl2[qd] = relq[3 * lane + 2];

        const unsigned long long bal = __ballot(vl != 0);
        const unsigned msk = (unsigned)((bal >> (seg * 16)) & 0xFFFFull);
        const unsigned below = (1u << q) - 1u;
        const int cntseg = __popc(msk);
        const int pos = vl ? __popc(msk & below)
                           : cntseg + __popc((~msk) & below);
        // bijective push within the 16-lane segment: valid->front (stable)
        cwd[qd] = __builtin_amdgcn_ds_permute(permb + (pos << 2),
                                              id | (vl << 14));
        scf[qd]  = (float)cntseg;
        vldf[qd] = (float)vl;
    }

    // gather buffer: zero-init ONCE; stale values are finite (prior feats)
    // and multiplied by m=0 -> result unchanged (r15/r20-verified pattern).
    u32x2 gv[NN];
#pragma unroll
    for (int n = 0; n < NN; ++n) gv[n] = (u32x2){0u, 0u};

    // ---- phase 1: 4 quads of 4 rows -> bf16 staging tile ----
    for (int qd = 0; qd < 4; ++qd) {
        const int   cmb = cwd[qd];                 // compacted id|valid<<14
        const float msf = vldf[qd];                // ORIGINAL slot validity
        float mr0 = msf * rl0[qd];
        float mr1 = msf * rl1[qd];
        float mr2 = msf * rl2[qd];

        // 16 bpermutes: broadcast compacted slot n to the 16-lane segment
        int cm[NN];
#pragma unroll
        for (int n = 0; n < NN; ++n)
            cm[n] = __builtin_amdgcn_ds_bpermute(permb + 4 * n, cmb);

        // 16 PREDICATED dwordx2 gathers. After compaction, slot n is
        // invalid for ALL rows iff n >= max(cnt of the 4 rows) ->
        // s_cbranch_execz skips whole instructions: E[executed] ~ 11/16.
#pragma unroll
        for (int n = 0; n < NN; ++n) {
            if (cm[n] & 0x4000) {
                const int off = ((cm[n] & 0x3FFF) << 6) + 4 * q; // ushorts
                gv[n] = *(const u32x2*)(fb + off);
            }
        }
        __builtin_amdgcn_sched_barrier(0);        // loads stay hoisted

        float s0 = 0.f, s1 = 0.f, s2 = 0.f, s3 = 0.f;
#pragma unroll
        for (int n = 0; n < NN; ++n) {            // unpack bf16 + fma
            const float m = (float)(cm[n] >> 14);
            const unsigned ux = gv[n].x, uy = gv[n].y;
            s0 = fmaf(m, __uint_as_float(ux << 16), s0);
            s1 = fmaf(m, __uint_as_float(ux & 0xFFFF0000u), s1);
            s2 = fmaf(m, __uint_as_float(uy << 16), s2);
            s3 = fmaf(m, __uint_as_float(uy & 0xFFFF0000u), s3);
        }

        // segment(16-lane) butterfly for the 3 masked rel sums
        // (cnt now comes free from the compaction popcount)
        mr0 = swz_add<0x041F>(mr0); mr1 = swz_add<0x041F>(mr1); mr2 = swz_add<0x041F>(mr2);
        mr0 = swz_add<0x081F>(mr0); mr1 = swz_add<0x081F>(mr1); mr2 = swz_add<0x081F>(mr2);
        mr0 = swz_add<0x101F>(mr0); mr1 = swz_add<0x101F>(mr1); mr2 = swz_add<0x101F>(mr2);
        mr0 = swz_add<0x201F>(mr0); mr1 = swz_add<0x201F>(mr1); mr2 = swz_add<0x201F>(mr2);

        const float cnt = scf[qd];
        const float inv = (cnt > 0.f) ? (1.0f / cnt) : 0.0f;

        const int rowl = qd * 4 + seg;           // row within 16-row tile
        u32x2 pv;
        pv.x = (unsigned)bf16_rne(s0 * inv) |
               ((unsigned)bf16_rne(s1 * inv) << 16);
        pv.y = (unsigned)bf16_rne(s2 * inv) |
               ((unsigned)bf16_rne(s3 * inv) << 16);
        *(u32x2*)(&Sw[rowl * PITCH_US + 4 * q]) = pv;     // ds_write_b64
        if (q == 0) {                      // rel -> ch 64..66 (+0 pad 67)
            u32x2 ev;
            ev.x = (unsigned)bf16_rne(mr0 * inv) |
                   ((unsigned)bf16_rne(mr1 * inv) << 16);
            ev.y = (unsigned)bf16_rne(mr2 * inv);
            *(u32x2*)(&Sw[rowl * PITCH_US + 64]) = ev;
        }
    }

    // ---- phase 2: 16x64 = S(16x96) x W^T(96x64) on the MFMA pipe ----
    f32x4 C0 = {0.f,0.f,0.f,0.f}, C1 = {0.f,0.f,0.f,0.f};
    f32x4 C2 = {0.f,0.f,0.f,0.f}, C3 = {0.f,0.f,0.f,0.f};
#pragma unroll
    for (int p = 0; p < 3; ++p) {
        const int ko = p * 32 + (lane >> 4) * 8;
        const s16x8 A  = *(const s16x8*)&Sw[(lane & 15) * PITCH_US + ko];
        const s16x8 B0 = *(const s16x8*)&Wbf[( 0 + (lane & 15)) * PITCH_US + ko];
        const s16x8 B1 = *(const s16x8*)&Wbf[(16 + (lane & 15)) * PITCH_US + ko];
        const s16x8 B2 = *(const s16x8*)&Wbf[(32 + (lane & 15)) * PITCH_US + ko];
        const s16x8 B3 = *(const s16x8*)&Wbf[(48 + (lane & 15)) * PITCH_US + ko];
        C0 = __builtin_amdgcn_mfma_f32_16x16x32_bf16(A, B0, C0, 0, 0, 0);
        C1 = __builtin_amdgcn_mfma_f32_16x16x32_bf16(A, B1, C1, 0, 0, 0);
        C2 = __builtin_amdgcn_mfma_f32_16x16x32_bf16(A, B2, C2, 0, 0, 0);
        C3 = __builtin_amdgcn_mfma_f32_16x16x32_bf16(A, B3, C3, 0, 0, 0);
    }

    // ---- epilogue: C/D layout col=lane&15, row=(lane>>4)*4+r ----
    const float bias0 = bvec[ 0 + (lane & 15)];
    const float bias1 = bvec[16 + (lane & 15)];
    const float bias2 = bvec[32 + (lane & 15)];
    const float bias3 = bvec[48 + (lane & 15)];
    const int m0 = (lane >> 4) * 4;
    const int oc = lane & 15;
#pragma unroll
    for (int r = 0; r < 4; ++r) {
        const size_t orow = ((size_t)b * KK + (size_t)(kg + m0 + r)) * OUTC;
        out[orow + 0  + oc] = fmaxf(C0[r] + bias0, 0.0f);
        out[orow + 16 + oc] = fmaxf(C1[r] + bias1, 0.0f);
        out[orow + 32 + oc] = fmaxf(C2[r] + bias2, 0.0f);
        out[orow + 48 + oc] = fmaxf(C3[r] + bias3, 0.0f);
    }
}

extern "C" void kernel_launch(void* const* d_in, const int* in_sizes, int n_in,
                              void* d_out, int out_size, void* d_ws, size_t ws_size,
                              hipStream_t stream) {
    // setup_inputs order: keys(0), points(1), feats(2), n_idxs(3),
    // neighbor_rel(4), neighbor_valid(5), W(6), b(7). keys/points unused.
    const float* feats = (const float*)d_in[2];
    const int*   nidx  = (const int*)  d_in[3];
    const float* nrel  = (const float*)d_in[4];
    const int*   nval  = (const int*)  d_in[5];
    const float* Wm    = (const float*)d_in[6];
    const float* bv    = (const float*)d_in[7];
    float* out = (float*)d_out;

    // workspace: bf16 feats image 16.78 MB (re-written every call)
    unsigned short* fbf16 = (unsigned short*)d_ws;

    // pre-pass: 8.39M floats / 4 per thread = 8192 blocks
    feats_to_bf16_kernel<<<dim3(8192), dim3(256), 0, stream>>>(feats, fbf16);

    // main: 1024 blocks x 512 threads (compaction now inline), XCD<->batch
    // binding, exact-fit 4 blocks/CU (LDS 39936B), 8 waves x 16 rows x
    // 1024 blocks = 131072 rows.
    graphconv_kernel<<<dim3(1024), dim3(512), 0, stream>>>(
        fbf16, nidx, nrel, nval, Wm, bv, out);
}